// Round 6
// baseline (82.460 us; speedup 1.0000x reference)
//
#include <hip/hip_runtime.h>
#include <math.h>

// NMSLoss4: B=8, N=2048, G=64. Sequential NMS == unique fixed point of
// sel[j] = pos[j] && !(exists edge i->j with sel[i]) over the key-directed
// forward DAG (key = score desc, idx asc). Jacobi to the fixed point, then
// order-free reductions. Round 5: in-edge lists held in REGISTERS across
// Jacobi passes (invariant), 2 barriers/pass via double-buffered flags,
// exact overflow side-list instead of hot-path scans.

#define B_IMG 8
#define NN 2048
#define GG 64
#define NMS_T 0.5f
#define MIN_H 50.0f
#define EPSF 1e-6f
#define CAP 12
#define OVF_MAX 1024
#define TILE 256
#define NTILE (NN / TILE)                 // 8
#define NPAIRT (NTILE * (NTILE + 1) / 2)  // 36
#define CSLICE 64
#define SLOTS 8

// per-image ws layout (bytes)
#define OFF_BOX   0              // float4[2048]   32768
#define OFF_KEY   32768          // u64[2048]      16384
#define OFF_GTPI  49152          // f32[2048]       8192
#define OFF_PULL  57344          // f32[2048]       8192
#define OFF_CNT   65536          // u32[2048]       8192
#define OFF_AGTI  73728          // s8[2048]        2048
#define OFF_OVFC  75776          // u32 count (padded)
#define OFF_OVF   76032          // u32[1024]       4096
#define OFF_INL   80128          // u16[2048*12]   49152 (24B/elem, 8-aligned)
#define IMG_STRIDE 129536

__device__ __forceinline__ float iou_pair(
    float ax1, float ay1, float ax2, float ay2,
    float bx1, float by1, float bx2, float by2) {
  float area_a = (ax2 - ax1) * (ay2 - ay1);
  float area_b = (bx2 - bx1) * (by2 - by1);
  float lx = fmaxf(ax1, bx1), ly = fmaxf(ay1, by1);
  float rx = fminf(ax2, bx2), ry = fminf(ay2, by2);
  float w = fmaxf(rx - lx, 0.0f), h = fmaxf(ry - ly, 0.0f);
  float inter = w * h;
  return inter / (area_a + area_b - inter + 1e-10f);
}

// ---------------- kernel 1: per-box prep + zero d_out/ovf -------------------
__global__ __launch_bounds__(256) void k_prep(
    const int* __restrict__ agti_all,
    const float* __restrict__ gtb_all,
    const float* __restrict__ prop_all,
    unsigned char* __restrict__ ws,
    float* __restrict__ out) {
  const int b = blockIdx.x >> 3, chunk = blockIdx.x & 7;
  const int tid = threadIdx.x;
  const int e = chunk * TILE + tid;
  const int* agti = agti_all + b * NN;
  const float* prop = prop_all + (size_t)b * NN * 5;
  unsigned char* W = ws + (size_t)b * IMG_STRIDE;

  if (blockIdx.x == 0 && tid == 0) { out[0] = 0.f; out[1] = 0.f; }
  if (chunk == 0 && tid == 0) *(unsigned*)(W + OFF_OVFC) = 0u;

  __shared__ float sgt[GG * 4];
  sgt[tid] = gtb_all[b * GG * 4 + tid];
  __syncthreads();

  float x1 = prop[e * 5 + 0], y1 = prop[e * 5 + 1];
  float x2 = prop[e * 5 + 2], y2 = prop[e * 5 + 3];
  float sc = prop[e * 5 + 4];
  int a = agti[e];
  unsigned long long key = 0ull;
  float gi = 0.f, pl = 0.f;
  if (a >= 0) {
    // higher key = earlier selection; ties -> lower idx (jnp.argmax).
    key = ((unsigned long long)__float_as_uint(sc) << 32) | (unsigned)(NN - 1 - e);
    gi = iou_pair(sgt[a * 4 + 0], sgt[a * 4 + 1], sgt[a * 4 + 2], sgt[a * 4 + 3],
                  x1, y1, x2, y2);
    pl = -logf(fminf(0.5f + fmaxf(gi, EPSF), 1.0f)) * sc;
  }
  ((float4*)(W + OFF_BOX))[e] = make_float4(x1, y1, x2, y2);
  ((unsigned long long*)(W + OFF_KEY))[e] = key;
  ((float*)(W + OFF_GTPI))[e] = gi;
  ((float*)(W + OFF_PULL))[e] = pl;
  ((unsigned*)(W + OFF_CNT))[e] = 0u;
  ((signed char*)(W + OFF_AGTI))[e] = (signed char)a;
}

// ---------------- kernel 2: tiled all-pairs -> in-edge lists ----------------
// Branch-free inner loop; exact divide-free IoU>0.5 predicate:
// fl32(inter/denom) > 0.5f  <=>  inter/denom > 0.5+2^-25 (RNE)
// <=>  (double)inter > (0.5+2^-25)*(double)denom   (product exact: 24+25 bits)
__global__ __launch_bounds__(256) void k_pairs(unsigned char* __restrict__ ws) {
  int bx = blockIdx.x;
  const int b = bx / (NPAIRT * 4);
  int rem = bx % (NPAIRT * 4);
  int p = rem >> 2;
  const int q = rem & 3;
  int r = 0;
  #pragma unroll
  for (int t = 0; t < NTILE; ++t) {
    int wdt = NTILE - t;
    if (p < wdt) { r = t; break; }
    p -= wdt;
  }
  const int c = r + p;
  const int tid = threadIdx.x;
  unsigned char* W = ws + (size_t)b * IMG_STRIDE;
  const float4* box = (const float4*)(W + OFF_BOX);
  const unsigned long long* keyA = (const unsigned long long*)(W + OFF_KEY);
  unsigned* cnt = (unsigned*)(W + OFF_CNT);
  unsigned short* inl = (unsigned short*)(W + OFF_INL);
  unsigned* ovfc = (unsigned*)(W + OFF_OVFC);
  unsigned* ovf = (unsigned*)(W + OFF_OVF);

  __shared__ float4 cbox[CSLICE];
  __shared__ float4 caux[CSLICE];   // (area_b, key_hi, key_lo, -)

  const int jbase = c * TILE + q * CSLICE;
  if (tid < CSLICE) {
    int j = jbase + tid;
    float4 Bx = box[j];
    unsigned long long kb = keyA[j];
    cbox[tid] = Bx;
    caux[tid] = make_float4((Bx.z - Bx.x) * (Bx.w - Bx.y),
                            __uint_as_float((unsigned)(kb >> 32)),
                            __uint_as_float((unsigned)kb), 0.f);
  }
  const int i = r * TILE + tid;
  const float4 A = box[i];
  const unsigned long long ka = keyA[i];
  const float area_a = (A.z - A.x) * (A.w - A.y);
  __syncthreads();

  const double THR = 0.5 + 0x1p-25;
  #pragma unroll 8
  for (int jj = 0; jj < CSLICE; ++jj) {
    float4 Bx = cbox[jj];
    float4 ax = caux[jj];
    float lx = fmaxf(A.x, Bx.x), ly = fmaxf(A.y, Bx.y);
    float rx = fminf(A.z, Bx.z), ry = fminf(A.w, Bx.w);
    float w = fmaxf(rx - lx, 0.0f), h = fmaxf(ry - ly, 0.0f);
    float inter = w * h;
    float denom = area_a + ax.x - inter + 1e-10f;  // ((aa+ab)-inter)+eps
    unsigned long long kb =
        ((unsigned long long)__float_as_uint(ax.y) << 32) | __float_as_uint(ax.z);
    int j = jbase + jj;
    bool hit = ((double)inter > THR * (double)denom) &&
               (ka != 0ull) && (kb != 0ull) && (j > i);
    if (hit) {
      int hi = (ka > kb) ? i : j;
      int lo = (ka > kb) ? j : i;
      unsigned pos = atomicAdd(&cnt[lo], 1u);
      if (pos < CAP) {
        inl[lo * CAP + pos] = (unsigned short)hi;
      } else {
        unsigned o = atomicAdd(ovfc, 1u);
        if (o < OVF_MAX) ovf[o] = ((unsigned)lo << 16) | (unsigned)hi;
      }
    }
  }
}

// exact fallback, only if the overflow list itself overflowed (≈ never)
__device__ bool scan_kill(const unsigned char* W,
                          const unsigned long long* selw,
                          int e, unsigned long long mykey, int excl) {
  const float4* box = (const float4*)(W + OFF_BOX);
  const unsigned long long* keyA = (const unsigned long long*)(W + OFF_KEY);
  float4 E = box[e];
  for (int w = 0; w < 32; ++w) {
    unsigned long long m = selw[w];
    while (m) {
      int bit = __ffsll((long long)m) - 1;
      m &= m - 1ull;
      int i = w * 64 + bit;
      if (i == excl) continue;
      if (keyA[i] > mykey) {
        float4 I = box[i];
        if (iou_pair(I.x, I.y, I.z, I.w, E.x, E.y, E.z, E.w) > NMS_T) return true;
      }
    }
  }
  return false;
}

// ---------------- kernel 3: Jacobi fixed point + bookkeeping + final --------
__global__ __launch_bounds__(256) void k_resolve(
    const float* __restrict__ gtb_all,
    unsigned char* __restrict__ ws,
    float* __restrict__ out) {
  const int b = blockIdx.x, tid = threadIdx.x;
  const int wave = tid >> 6, lane = tid & 63;
  unsigned char* W = ws + (size_t)b * IMG_STRIDE;
  const unsigned long long* keyA = (const unsigned long long*)(W + OFF_KEY);
  const float* gtpi = (const float*)(W + OFF_GTPI);
  const float* pull = (const float*)(W + OFF_PULL);
  const unsigned* cnt = (const unsigned*)(W + OFF_CNT);
  const signed char* ag8 = (const signed char*)(W + OFF_AGTI);
  const unsigned long long* inl64 = (const unsigned long long*)(W + OFF_INL);

  __shared__ unsigned long long selw[32];
  __shared__ unsigned long long maxkeysel[GG], maxkeypos[GG];
  __shared__ unsigned selcnt[GG];
  __shared__ unsigned long long s_minkey;
  __shared__ int s_flag[2], s_hasrem, s_npos;
  __shared__ unsigned l_ovf[OVF_MAX];
  __shared__ float wtp[4];

  unsigned long long mykey[SLOTS];
  unsigned mycnt[SLOTS];
  unsigned long long ep0[SLOTS], ep1[SLOTS], ep2[SLOTS];

  if (tid == 0) {
    s_flag[0] = 0; s_flag[1] = 0; s_hasrem = 0; s_npos = 0; s_minkey = ~0ull;
  }
  if (tid < GG) { maxkeysel[tid] = 0ull; maxkeypos[tid] = 0ull; selcnt[tid] = 0u; }

  const unsigned ovfc_raw = *(const unsigned*)(W + OFF_OVFC);
  const int novf = (int)(ovfc_raw < OVF_MAX ? ovfc_raw : OVF_MAX);
  const bool ovflow = ovfc_raw > OVF_MAX;
  for (int o = tid; o < novf; o += 256) l_ovf[o] = ((const unsigned*)(W + OFF_OVF))[o];

  int nposp = 0;
  #pragma unroll
  for (int k = 0; k < SLOTS; ++k) {
    int e = tid + (k << 8);         // word index = k*4+wave, bit = lane
    mykey[k] = keyA[e];
    mycnt[k] = cnt[e];
    ep0[k] = inl64[e * 3 + 0];
    ep1[k] = inl64[e * 3 + 1];
    ep2[k] = inl64[e * 3 + 2];
    unsigned long long wb = __ballot(mykey[k] != 0ull);
    if (lane == 0) selw[k * 4 + wave] = wb;   // init: all positives selected
    nposp += (mykey[k] != 0ull) ? 1 : 0;
  }
  #pragma unroll
  for (int off = 32; off; off >>= 1) nposp += __shfl_xor(nposp, off, 64);
  if (lane == 0) atomicAdd(&s_npos, nposp);
  __syncthreads();

  // ---- Jacobi to the sequential-NMS fixed point (2 barriers/pass) ----
  int cur = 0;
  for (;;) {
    unsigned ovk = 0u;
    if (novf) {
      for (int o = 0; o < novf; ++o) {
        unsigned pk = l_ovf[o];
        int v = (int)(pk >> 16);
        if ((v & 255) == tid) {
          int i = (int)(pk & 0xffffu);
          ovk |= (unsigned)((selw[i >> 6] >> (i & 63)) & 1ull) << (v >> 8);
        }
      }
    }
    unsigned long long nw[SLOTS];
    #pragma unroll
    for (int k = 0; k < SLOTS; ++k) {
      bool sel = false;
      if (mykey[k] != 0ull) {
        unsigned long long kill = (unsigned long long)((ovk >> k) & 1u);
        int ce = mycnt[k] < CAP ? (int)mycnt[k] : CAP;
        unsigned long long p0 = ep0[k], p1 = ep1[k], p2 = ep2[k];
        for (int kk = 0; kk < ce; ++kk) {
          unsigned long long w = kk < 4 ? p0 : (kk < 8 ? p1 : p2);
          int idx = (int)((w >> ((kk & 3) << 4)) & 0xffffull);
          kill |= (selw[idx >> 6] >> (idx & 63)) & 1ull;
        }
        bool killed = (kill != 0ull);
        if (!killed && ovflow && mycnt[k] > CAP)
          killed = scan_kill(W, selw, tid + (k << 8), mykey[k], -1);
        sel = !killed;
      }
      nw[k] = __ballot(sel);
    }
    __syncthreads();                       // B1: all reads of old selw done
    if (lane == 0) {
      #pragma unroll
      for (int k = 0; k < SLOTS; ++k)
        if (nw[k] != selw[k * 4 + wave]) { selw[k * 4 + wave] = nw[k]; s_flag[cur] = 1; }
    }
    if (tid == 0) s_flag[cur ^ 1] = 0;     // pre-clear next pass's flag
    __syncthreads();                       // B2: commits visible
    if (!s_flag[cur]) break;
    cur ^= 1;
  }

  // ---- bookkeeping pass 1: per-g stats over selected / positive ----
  float tp_part = 0.f;
  #pragma unroll
  for (int k = 0; k < SLOTS; ++k) {
    int e = tid + (k << 8);
    if (mykey[k] != 0ull) {
      int g = ag8[e];
      atomicMax(&maxkeypos[g], mykey[k]);
      bool sel = (selw[k * 4 + wave] >> lane) & 1ull;
      if (sel) {
        atomicAdd(&selcnt[g], 1u);
        atomicMax(&maxkeysel[g], mykey[k]);
        atomicMin(&s_minkey, mykey[k]);
        tp_part += pull[e];
      }
    }
  }
  __syncthreads();

  // ---- pass 2: subtract first-of-g pulls; has_rem for the last selection ----
  const unsigned long long minkey = s_minkey;
  const int idx_last =
      (minkey != ~0ull) ? (NN - 1 - (int)(minkey & 0xffffffffull)) : -1;
  unsigned ovoth = 0u;
  if (novf) {
    for (int o = 0; o < novf; ++o) {
      unsigned pk = l_ovf[o];
      int v = (int)(pk >> 16);
      if ((v & 255) == tid) {
        int i = (int)(pk & 0xffffu);
        if (i != idx_last && ((selw[i >> 6] >> (i & 63)) & 1ull))
          ovoth |= 1u << (v >> 8);
      }
    }
  }
  #pragma unroll
  for (int k = 0; k < SLOTS; ++k) {
    int e = tid + (k << 8);
    if (mykey[k] == 0ull) continue;
    bool sel = (selw[k * 4 + wave] >> lane) & 1ull;
    if (sel) {
      int g = ag8[e];
      if (mykey[k] == maxkeysel[g]) tp_part -= pull[e];  // first of its g
    } else {
      // killed box: active at i_last's turn iff its ONLY selected killer is i_last
      bool other = ((ovoth >> k) & 1u) != 0u;
      int ce = mycnt[k] < CAP ? (int)mycnt[k] : CAP;
      unsigned long long p0 = ep0[k], p1 = ep1[k], p2 = ep2[k];
      for (int kk = 0; kk < ce && !other; ++kk) {
        unsigned long long w = kk < 4 ? p0 : (kk < 8 ? p1 : p2);
        int idx = (int)((w >> ((kk & 3) << 4)) & 0xffffull);
        if (idx != idx_last && ((selw[idx >> 6] >> (idx & 63)) & 1ull)) other = true;
      }
      if (!other && ovflow && mycnt[k] > CAP)
        other = scan_kill(W, selw, e, mykey[k], idx_last);
      if (!other) s_hasrem = 1;
    }
  }
  #pragma unroll
  for (int off = 32; off; off >>= 1) tp_part += __shfl_xor(tp_part, off, 64);
  if (lane == 0) wtp[wave] = tp_part;
  __syncthreads();

  // ---- push term + finalize (wave 0; lane == g), fused final reduction ----
  if (wave == 0) {
    float mypush = 0.f;
    int mycnt2 = 0;
    unsigned long long kb = maxkeypos[lane];
    bool seen = selcnt[lane] > 0u;
    if (kb != 0ull) {
      float h = gtb_all[b * GG * 4 + lane * 4 + 3] - gtb_all[b * GG * 4 + lane * 4 + 1];
      if (h >= MIN_H && !seen) {
        int bj = NN - 1 - (int)(kb & 0xffffffffull);
        mypush = 1.0f - gtpi[bj];
        mycnt2 = 1;
      }
    }
    #pragma unroll
    for (int off = 32; off; off >>= 1) {
      mypush += __shfl_xor(mypush, off, 64);
      mycnt2 += __shfl_xor(mycnt2, off, 64);
    }
    if (lane == 0) {
      float tp = wtp[0] + wtp[1] + wtp[2] + wtp[3];
      int total_sel = 0;
      for (int w = 0; w < 32; ++w) total_sel += __popcll(selw[w]);
      int distinct = 0;
      for (int g = 0; g < GG; ++g) distinct += (selcnt[g] > 0u) ? 1 : 0;
      int pc = total_sel - distinct;
      if (idx_last >= 0) {
        int gl = ag8[idx_last];
        // last selection: its pull only counts if non-first-of-g AND has_rem
        if (minkey != maxkeysel[gl] && !s_hasrem) tp -= pull[idx_last];
      }
      float push_loss = 0.f, pull_loss = 0.f;
      if (s_npos > 1) {
        pull_loss = tp / ((float)pc + EPSF);
        push_loss = mypush / ((float)mycnt2 + EPSF);
      }
      atomicAdd(&out[0], push_loss * (1.0f / B_IMG));
      atomicAdd(&out[1], pull_loss * (1.0f / B_IMG));
    }
  }
}

extern "C" void kernel_launch(void* const* d_in, const int* in_sizes, int n_in,
                              void* d_out, int out_size, void* d_ws, size_t ws_size,
                              hipStream_t stream) {
  const int* agti = (const int*)d_in[1];
  const float* gtb = (const float*)d_in[2];
  const float* prop = (const float*)d_in[3];
  unsigned char* ws = (unsigned char*)d_ws;
  float* out = (float*)d_out;

  k_prep<<<B_IMG * 8, 256, 0, stream>>>(agti, gtb, prop, ws, out);
  k_pairs<<<B_IMG * NPAIRT * 4, 256, 0, stream>>>(ws);
  k_resolve<<<B_IMG, 256, 0, stream>>>(gtb, ws, out);
}